// Round 6
// baseline (695.215 us; speedup 1.0000x reference)
//
#include <hip/hip_runtime.h>
#include <math.h>

#define T_LEN 8192
#define NUM_CH 64
#define HID 256
#define NUM_CLS 40
#define NUM_PROP 1024
#define NUM_PROP_AFTER 256
#define PROP_LEN 128

#define NPAIR 64    // group pairs; block = (slice, pair)
#define NSL 4       // hidden slices (64 units each)
#define KH 320      // K in halves: 256 h + 64 x
#define KSEGN 4     // K segments per row
#define SEGH 80     // halves per segment
#define HXPAR 65536 // u32s per parity buffer: 256 seqs x 256 units

typedef _Float16 h2_t __attribute__((ext_vector_type(2)));
union U32H2 { unsigned int u; h2_t h; };
union HU16 { _Float16 h; unsigned short u; };

#if defined(__has_builtin)
#if __has_builtin(__builtin_amdgcn_fdot2)
#define HAS_FDOT2 1
#endif
#endif

__device__ __forceinline__ float dot2f(unsigned int wa, unsigned int hb, float acc) {
    U32H2 a, b;
    a.u = wa;
    b.u = hb;
#ifdef HAS_FDOT2
    return __builtin_amdgcn_fdot2(a.h, b.h, acc, false);
#else
    return acc + (float)a.h[0] * (float)b.h[0] + (float)a.h[1] * (float)b.h[1];
#endif
}

__device__ __forceinline__ float dot8f(const uint4& w, const uint4& h, float acc) {
    acc = dot2f(w.x, h.x, acc);
    acc = dot2f(w.y, h.y, acc);
    acc = dot2f(w.z, h.z, acc);
    acc = dot2f(w.w, h.w, acc);
    return acc;
}

__device__ __forceinline__ float fsigmoid(float x) { return 1.0f / (1.0f + __expf(-x)); }
__device__ __forceinline__ float ftanh(float x) {
    float e = __expf(-2.0f * fabsf(x));
    float t = (1.0f - e) / (1.0f + e);
    return copysignf(t, x);
}

__device__ __forceinline__ unsigned int pack2(float a, float b) {
    HU16 ha, hb;
    ha.h = (_Float16)a;
    hb.h = (_Float16)b;
    return (unsigned int)ha.u | ((unsigned int)hb.u << 16);
}

// ---------------------------------------------------------------------------
// Fused cooperative kernel, A/B phase-pipelined:
// 256 blocks = 4 slices x 64 pairs; each block serves TWO groups of 2 seqs.
// Per t, two half-steps (X = A then B):
//   W1: all 16 waves dot_X          (reads hx[X], fully local)
//   W2: waves 0-1  reduce+act+publish h_X(t+1) (tagged u32, relaxed agent)
//       waves 10-11 x_X(t+1) -> LDS
//       waves 12-15 gather other group Y's h (tag-validated, hard-finish)
// Exchange latency of X hides under dot_Y + barriers. t=0 gathers skipped
// (h0=0); post-loop gather fetches h_B(128) for the heads.
// ---------------------------------------------------------------------------
__global__ __launch_bounds__(1024, 4) void fused_kernel(
    const float* __restrict__ data, const float* __restrict__ prop,
    const float* __restrict__ W_ih, const float* __restrict__ W_hh,
    const float* __restrict__ b_ih, const float* __restrict__ b_hh,
    const float* __restrict__ W_cls, const float* __restrict__ b_cls,
    const float* __restrict__ W_bbox, const float* __restrict__ b_bbox,
    float* __restrict__ out, unsigned int* __restrict__ t0s,
    unsigned int* __restrict__ Hx32) {
    __shared__ __align__(16) _Float16 hx[2][2][KH];        // [grp][seq][320] = 2.5 KB
    __shared__ __align__(16) float pp[2][2][KSEGN][256];   // [grp][seq][kseg][row] = 16 KB

    const int tid = threadIdx.x;
    const int p = blockIdx.x & (NPAIR - 1);  // pair
    const int s = blockIdx.x >> 6;           // slice
    const int kseg = tid >> 8;               // wave-uniform K segment
    const int rl = tid & 255;                // row_local = gate*64 + unit

    // ===================== block 0: NMS (overlaid on pp) =====================
    if (blockIdx.x == 0) {
        float* nb = &pp[0][0][0][0];
        float* sc_p = nb;
        float* ss = nb + 1024;
        float* se = nb + 2048;
        unsigned char* sup = (unsigned char*)(nb + 3072);
        unsigned long long* cmask = (unsigned long long*)((char*)(nb + 3072) + 1024);

        float ps = prop[tid * 3 + 0];
        float pe = prop[tid * 3 + 1];
        float pc = prop[tid * 3 + 2];
        sc_p[tid] = pc;
        sup[tid] = 0;
        __syncthreads();

        int r = 0;
        for (int j = 0; j < NUM_PROP; ++j) {
            float o = sc_p[j];
            r += (o > pc) || (o == pc && j < tid);
        }
        ss[r] = ps;
        se[r] = pe;
        __syncthreads();

        const float my_s = ss[tid];
        const float my_e = se[tid];
        const float my_len = my_e - my_s;
        bool mysup = false;

        for (int ci = 0; ci < 16; ++ci) {
            if (tid < 64) {
                int i = ci * 64 + tid;
                float is_ = ss[i], ie_ = se[i];
                unsigned long long m = __ballot(sup[i] != 0);
                for (int l = 0; l < 64; ++l) {
                    if (!((m >> l) & 1)) {
                        float ls = __shfl(is_, l);
                        float le = __shfl(ie_, l);
                        float inter = fmaxf(fminf(le, ie_) - fmaxf(ls, is_), 0.0f);
                        float uni = (le - ls) + (ie_ - is_) - inter;
                        float iou = inter / fmaxf(uni, 1e-6f);
                        unsigned long long nb2 = __ballot((tid > l) && (iou > 0.5f));
                        m |= nb2;
                    }
                }
                sup[i] = (unsigned char)((m >> tid) & 1);
                if (tid == 0) cmask[ci] = ~m;
            }
            __syncthreads();
            unsigned long long am = cmask[ci];
            for (int l = 0; l < 64; ++l) {
                if ((am >> l) & 1) {
                    int i = ci * 64 + l;
                    if (tid > i && !mysup) {
                        float ls = ss[i], le = se[i];
                        float inter = fmaxf(fminf(le, my_e) - fmaxf(ls, my_s), 0.0f);
                        float uni = (le - ls) + my_len - inter;
                        if (inter / fmaxf(uni, 1e-6f) > 0.5f) mysup = true;
                    }
                }
            }
            sup[tid] = mysup ? 1 : 0;
            __syncthreads();
        }

        int myc = tid >> 6;
        unsigned long long mybit = 1ull << (tid & 63);
        int kb = 0, kt = 0;
        for (int c2 = 0; c2 < 16; ++c2) {
            int pc2 = __popcll(cmask[c2]);
            kt += pc2;
            if (c2 < myc) kb += pc2;
        }
        kb += __popcll(cmask[myc] & (mybit - 1));
        int slot = (cmask[myc] & mybit) ? kb : (kt + (tid - kb));
        if (slot < NUM_PROP_AFTER) {
            int t0v = (int)rintf(my_s);
            t0v = max(0, min(t0v, T_LEN - PROP_LEN));
            __hip_atomic_store(&t0s[slot], (unsigned int)t0v | 0x80000000u,
                               __ATOMIC_RELAXED, __HIP_MEMORY_SCOPE_AGENT);
        }
        asm volatile("s_waitcnt vmcnt(0)" ::: "memory");
        __syncthreads();
    }

    // ============ W fragment: direct f32 load + f16 pack (same as R5) ========
    uint4 Wr[10];
    {
        const int gate = rl >> 6, unit = rl & 63;
        const int grow = gate * 256 + s * 64 + unit;
        const float* __restrict__ baseh = W_hh + grow * HID;
        const float* __restrict__ basex = W_ih + grow * NUM_CH;
#pragma unroll
        for (int j = 0; j < 10; ++j) {
            const int kh = kseg * SEGH + j * 8;
            const float* src = (kh < 256) ? (baseh + kh) : (basex + (kh - 256));
            float4 f0 = *(const float4*)(src);
            float4 f1 = *(const float4*)(src + 4);
            Wr[j] = make_uint4(pack2(f0.x, f0.y), pack2(f0.z, f0.w),
                               pack2(f1.x, f1.y), pack2(f1.z, f1.w));
        }
    }

    // reduce role (tid<128): sq = tid>>6, au = tid&63; holds c-state for A and B
    float bi = 0.f, bf = 0.f, bg = 0.f, bo = 0.f;
    float c_stA = 0.f, c_stB = 0.f;
    if (tid < 128) {
        int u = s * 64 + (tid & 63);
        bi = b_ih[u] + b_hh[u];
        bf = b_ih[256 + u] + b_hh[256 + u];
        bg = b_ih[512 + u] + b_hh[512 + u];
        bo = b_ih[768 + u] + b_hh[768 + u];
    }

    // zero h region of hx: exactly 1024 halves, one per thread
    hx[tid >> 9][(tid >> 8) & 1][tid & 255] = (_Float16)0.0f;

    // x role (waves 10-11): sqx = wave parity, chx = lane; both groups' t0
    const int sqx = (tid >> 6) & 1;
    const int chx = tid & 63;
    int xt0A = 0, xt0B = 0;
    if (tid >= 640 && tid < 768) {
        unsigned int tv;
        const unsigned int* tpA = &t0s[4 * p + sqx];
        for (;;) {
            tv = __hip_atomic_load(tpA, __ATOMIC_RELAXED, __HIP_MEMORY_SCOPE_AGENT);
            if (tv & 0x80000000u) break;
            __builtin_amdgcn_s_sleep(8);
        }
        xt0A = (int)(tv & 0x7FFFFFFFu);
        const unsigned int* tpB = &t0s[4 * p + 2 + sqx];
        for (;;) {
            tv = __hip_atomic_load(tpB, __ATOMIC_RELAXED, __HIP_MEMORY_SCOPE_AGENT);
            if (tv & 0x80000000u) break;
            __builtin_amdgcn_s_sleep(8);
        }
        xt0B = (int)(tv & 0x7FFFFFFFu);
        hx[0][sqx][256 + chx] = (_Float16)data[xt0A * NUM_CH + chx];  // x_A(0)
        hx[1][sqx][256 + chx] = (_Float16)data[xt0B * NUM_CH + chx];  // x_B(0)
    }

    // gather engine (waves 12-15): lane li covers word li (+ li+256 if li<128)
    // of the 384 peer words (2 seqs x 192 units) of the target group.
    auto gather_grp = [&](int Y, unsigned int tg) {
        const int par = (int)(tg & 1u);
        const int li = tid - 768;
        const unsigned int* base = Hx32 + par * HXPAR;
        // word0
        const int sq0 = (li >= 192) ? 1 : 0;
        const int pu0 = li - sq0 * 192;
        const int u0 = pu0 + (pu0 >= s * 64 ? 64 : 0);
        const unsigned int* a0p = base + (4 * p + 2 * Y + sq0) * HID + u0;
        // word1 (only li<128): w = 256+li -> sq=1, pu = 64+li
        const bool have1 = (li < 128);
        const int pu1 = 64 + li;
        const int u1 = pu1 + (pu1 >= s * 64 ? 64 : 0);
        const unsigned int* a1p = base + (4 * p + 2 * Y + 1) * HID + u1;
        bool d0 = false, d1 = !have1;
        for (;;) {
            if (!d0) {
                unsigned int v =
                    __hip_atomic_load(a0p, __ATOMIC_RELAXED, __HIP_MEMORY_SCOPE_AGENT);
                if ((v >> 16) == tg) {
                    HU16 hv;
                    hv.u = (unsigned short)(v & 0xFFFFu);
                    hx[Y][sq0][u0] = hv.h;
                    d0 = true;
                }
            }
            if (!d1) {
                unsigned int v =
                    __hip_atomic_load(a1p, __ATOMIC_RELAXED, __HIP_MEMORY_SCOPE_AGENT);
                if ((v >> 16) == tg) {
                    HU16 hv;
                    hv.u = (unsigned short)(v & 0xFFFFu);
                    hx[Y][1][u1] = hv.h;
                    d1 = true;
                }
            }
            if (d0 && d1) break;
            __builtin_amdgcn_s_sleep(1);
        }
    };

    // half-step body: X = phase (0=A, 1=B); CST = that phase's c-state ref
    auto half_step = [&](int t, int X, float& CST, int XT0) {
        // --- W1: dot on group X (all 16 waves) ---
        float a0 = 0.f, a1 = 0.f;
#pragma unroll
        for (int j = 0; j < 10; ++j) {
            const int hb = kseg * SEGH + j * 8;
            uint4 h0 = *(const uint4*)&hx[X][0][hb];
            uint4 h1 = *(const uint4*)&hx[X][1][hb];
            uint4 w = Wr[j];
            a0 = dot8f(w, h0, a0);
            a1 = dot8f(w, h1, a1);
        }
        pp[X][0][kseg][rl] = a0;
        pp[X][1][kseg][rl] = a1;
        __syncthreads();

        // --- W2: role split ---
        const unsigned int tagp = (unsigned int)(t + 1);
        const int parp = (t + 1) & 1;
        if (tid < 128) {
            const int sq = tid >> 6;
            const int au = tid & 63;
            float si = pp[X][sq][0][au] + pp[X][sq][1][au] + pp[X][sq][2][au] +
                       pp[X][sq][3][au] + bi;
            float sf = pp[X][sq][0][64 + au] + pp[X][sq][1][64 + au] +
                       pp[X][sq][2][64 + au] + pp[X][sq][3][64 + au] + bf;
            float sg = pp[X][sq][0][128 + au] + pp[X][sq][1][128 + au] +
                       pp[X][sq][2][128 + au] + pp[X][sq][3][128 + au] + bg;
            float so = pp[X][sq][0][192 + au] + pp[X][sq][1][192 + au] +
                       pp[X][sq][2][192 + au] + pp[X][sq][3][192 + au] + bo;
            float gi = fsigmoid(si), gf = fsigmoid(sf);
            float gg = ftanh(sg), go = fsigmoid(so);
            CST = gf * CST + gi * gg;
            float hval = go * ftanh(CST);
            HU16 hu;
            hu.h = (_Float16)hval;
            // publish FIRST (starts the exchange clock), then local writes
            __hip_atomic_store(
                &Hx32[parp * HXPAR + (4 * p + 2 * X + sq) * HID + s * 64 + au],
                (tagp << 16) | (unsigned int)hu.u, __ATOMIC_RELAXED,
                __HIP_MEMORY_SCOPE_AGENT);
            hx[X][sq][s * 64 + au] = hu.h;
        } else if (tid >= 640 && tid < 768) {
            if (t + 1 < PROP_LEN)
                hx[X][sqx][256 + chx] = (_Float16)data[(XT0 + t + 1) * NUM_CH + chx];
        } else if (tid >= 768) {
            const unsigned int tg = (unsigned int)(t + X);  // A: h_B(t), B: h_A(t+1)
            if (tg >= 1u) gather_grp(1 - X, tg);
        }
        __syncthreads();
    };

    __syncthreads();  // prologue complete (hx zeroed, x(0) loaded, NMS handed off)

    for (int t = 0; t < PROP_LEN; ++t) {
        half_step(t, 0, c_stA, xt0A);
        half_step(t, 1, c_stB, xt0B);
    }

    // hxB is missing peers' h_B(128): final gather (tag 128, parity 0)
    if (tid >= 768) gather_grp(1, (unsigned int)PROP_LEN);
    __syncthreads();

    // heads: 4 seqs (2 groups x 2), rows m in [30s, 30s+30)
    if (tid < 4 * 30) {
        int sq4 = tid / 30;
        int ml = tid % 30;
        int grp = sq4 >> 1, sq = sq4 & 1;
        int seqg = 4 * p + 2 * grp + sq;
        int m = s * 30 + ml;
        const float* Wrow;
        float acc;
        int oidx;
        if (m < NUM_CLS) {
            Wrow = W_cls + m * HID;
            acc = b_cls[m];
            oidx = seqg * NUM_CLS + m;
        } else {
            int mb = m - NUM_CLS;
            Wrow = W_bbox + mb * HID;
            acc = b_bbox[mb];
            oidx = NUM_PROP_AFTER * NUM_CLS + seqg * 2 * NUM_CLS + mb;
        }
        const float4* w4 = (const float4*)Wrow;
        const _Float16* hp = &hx[grp][sq][0];
        for (int c = 0; c < 32; ++c) {
            float4 wa = w4[c * 2 + 0];
            float4 wb = w4[c * 2 + 1];
            acc += (float)hp[c * 8 + 0] * wa.x + (float)hp[c * 8 + 1] * wa.y +
                   (float)hp[c * 8 + 2] * wa.z + (float)hp[c * 8 + 3] * wa.w +
                   (float)hp[c * 8 + 4] * wb.x + (float)hp[c * 8 + 5] * wb.y +
                   (float)hp[c * 8 + 6] * wb.z + (float)hp[c * 8 + 7] * wb.w;
        }
        out[oidx] = acc;
    }
}

extern "C" void kernel_launch(void* const* d_in, const int* in_sizes, int n_in,
                              void* d_out, int out_size, void* d_ws,
                              size_t ws_size, hipStream_t stream) {
    const float* data = (const float*)d_in[0];     // [8192, 64]
    const float* prop = (const float*)d_in[1];     // [1024, 3]
    const float* W_ih = (const float*)d_in[2];     // [1024, 64]
    const float* W_hh = (const float*)d_in[3];     // [1024, 256]
    const float* b_ih = (const float*)d_in[4];     // [1024]
    const float* b_hh = (const float*)d_in[5];     // [1024]
    const float* W_cls = (const float*)d_in[6];    // [40, 256]
    const float* b_cls = (const float*)d_in[7];    // [40]
    const float* W_bbox = (const float*)d_in[8];   // [80, 256]
    const float* b_bbox = (const float*)d_in[9];   // [80]
    float* out = (float*)d_out;

    // workspace layout (same as R5)
    unsigned int* t0s = (unsigned int*)d_ws;                   // [0, 1KB) tagged t0s
    unsigned int* Hx32 = (unsigned int*)((char*)d_ws + 4096);  // 512 KB tagged h (2 parities)

    // zero all tags each invocation (graph-captured, replayed per rep)
    hipMemsetAsync(d_ws, 0, 4096 + 2 * HXPAR * 4, stream);

    void* kargs[] = {(void*)&data,  (void*)&prop,   (void*)&W_ih,  (void*)&W_hh,
                     (void*)&b_ih,  (void*)&b_hh,   (void*)&W_cls, (void*)&b_cls,
                     (void*)&W_bbox, (void*)&b_bbox, (void*)&out,  (void*)&t0s,
                     (void*)&Hx32};
    hipLaunchCooperativeKernel((void*)fused_kernel, dim3(NSL * NPAIR), dim3(1024),
                               kargs, 0, stream);
}